// Round 1
// baseline (1213.584 us; speedup 1.0000x reference)
//
#include <hip/hip_runtime.h>
#include <hip/hip_bf16.h>

// Problem constants (fixed by the reference)
//   N_NODES = 50000, N_EDGES = 800000, C_IN = 64, N_HEADS = 4, HEAD_DIM = 16, FC = 64
// Edge tile: 128 edges/block (800000 % 128 == 0), 512 threads.

// ---------------------------------------------------------------------------
// Kernel A: node-side linears.  q = (x@Wq+bq)*0.25, msg_src = x@Wsrc+bsrc,
// msg_dst = x@Wdst.  Combined as one [64][192] GEMM per 32-node tile.
// ---------------------------------------------------------------------------
__global__ __launch_bounds__(384)
void node_linear_kernel(const float* __restrict__ x,
                        const float* __restrict__ Wq,   const float* __restrict__ bq,
                        const float* __restrict__ Wsrc, const float* __restrict__ bsrc,
                        const float* __restrict__ Wdst,
                        float* __restrict__ qout, float* __restrict__ msout,
                        float* __restrict__ mdout, int N)
{
    __shared__ __align__(16) float sW[64 * 192];   // [k][j], j: 0..63 Wq, 64..127 Wsrc, 128..191 Wdst
    __shared__ float sb[192];
    __shared__ __align__(16) float xs[32][68];

    const int t = threadIdx.x;

    // stage combined weights (float4 granularity; region boundaries are /4)
    for (int idx4 = t; idx4 < 3072; idx4 += 384) {
        const int k  = idx4 / 48;
        const int j4 = idx4 % 48;
        const float4* src = (j4 < 16) ? (const float4*)&Wq  [k * 64 + j4 * 4]
                         : (j4 < 32) ? (const float4*)&Wsrc[k * 64 + (j4 - 16) * 4]
                                     : (const float4*)&Wdst[k * 64 + (j4 - 32) * 4];
        ((float4*)sW)[idx4] = *src;
    }
    if (t < 192) sb[t] = (t < 64) ? bq[t] : (t < 128) ? bsrc[t - 64] : 0.0f;

    const int nbase = blockIdx.x * 32;
    for (int idx = t; idx < 512; idx += 384) {            // 32 rows x 16 float4
        const int n  = idx >> 4;
        const int c4 = (idx & 15) * 4;
        const int gn = nbase + n;
        float4 g = make_float4(0.f, 0.f, 0.f, 0.f);
        if (gn < N) g = *(const float4*)&x[(size_t)gn * 64 + c4];
        *(float4*)&xs[n][c4] = g;
    }
    __syncthreads();

    const int te = t / 48;        // 0..7  -> 4 nodes each
    const int tj = t % 48;        // 0..47 -> 4 cols each
    const int j0 = tj * 4;
    const int e0 = te * 4;

    float acc[4][4];
#pragma unroll
    for (int i = 0; i < 4; ++i)
#pragma unroll
        for (int c = 0; c < 4; ++c) acc[i][c] = 0.f;

#pragma unroll 16
    for (int k = 0; k < 64; ++k) {
        const float4 wv = *(const float4*)&sW[k * 192 + j0];
        const float a0 = xs[e0 + 0][k];
        const float a1 = xs[e0 + 1][k];
        const float a2 = xs[e0 + 2][k];
        const float a3 = xs[e0 + 3][k];
        acc[0][0] += a0 * wv.x; acc[0][1] += a0 * wv.y; acc[0][2] += a0 * wv.z; acc[0][3] += a0 * wv.w;
        acc[1][0] += a1 * wv.x; acc[1][1] += a1 * wv.y; acc[1][2] += a1 * wv.z; acc[1][3] += a1 * wv.w;
        acc[2][0] += a2 * wv.x; acc[2][1] += a2 * wv.y; acc[2][2] += a2 * wv.z; acc[2][3] += a2 * wv.w;
        acc[3][0] += a3 * wv.x; acc[3][1] += a3 * wv.y; acc[3][2] += a3 * wv.z; acc[3][3] += a3 * wv.w;
    }

#pragma unroll
    for (int i = 0; i < 4; ++i) {
        const int gn = nbase + e0 + i;
        if (gn >= N) continue;
        float4 o;
        o.x = acc[i][0] + sb[j0 + 0];
        o.y = acc[i][1] + sb[j0 + 1];
        o.z = acc[i][2] + sb[j0 + 2];
        o.w = acc[i][3] + sb[j0 + 3];
        if (j0 < 64) {
            o.x *= 0.25f; o.y *= 0.25f; o.z *= 0.25f; o.w *= 0.25f;   // 1/sqrt(HEAD_DIM)
            *(float4*)&qout[(size_t)gn * 64 + j0] = o;
        } else if (j0 < 128) {
            *(float4*)&msout[(size_t)gn * 64 + (j0 - 64)] = o;
        } else {
            *(float4*)&mdout[(size_t)gn * 64 + (j0 - 128)] = o;
        }
    }
}

// ---------------------------------------------------------------------------
// Kernel B: fused per-edge chain.
//   h1 = silu(es@W1+b1); h2 = silu(h1@W2+b2); w = h2@W3+b3
//   tp = (msg_src[src]+msg_dst[dst]) * ea * w
//   kv2 = tp@Wkv + bkv -> k (cols 0..63), v (cols 64..127)
//   alpha[h] = dot(q[dst][16h..], k[16h..]);  ex = exp(alpha)   (no seg-max:
//   mathematically identical ratios, |alpha| << 88 so no overflow)
//   atomics: num[dst] += ex*v ; den[dst][h] += ex
// ---------------------------------------------------------------------------
__device__ __forceinline__ void gemm_tile64(const float* __restrict__ in,
                                            const float* __restrict__ w,
                                            int e0, int j0, float acc[4][4])
{
#pragma unroll
    for (int i = 0; i < 4; ++i)
#pragma unroll
        for (int c = 0; c < 4; ++c) acc[i][c] = 0.f;
#pragma unroll 16
    for (int k = 0; k < 64; ++k) {
        const float4 wv = *(const float4*)&w[k * 64 + j0];
        const float a0 = in[(e0 + 0) * 68 + k];
        const float a1 = in[(e0 + 1) * 68 + k];
        const float a2 = in[(e0 + 2) * 68 + k];
        const float a3 = in[(e0 + 3) * 68 + k];
        acc[0][0] += a0 * wv.x; acc[0][1] += a0 * wv.y; acc[0][2] += a0 * wv.z; acc[0][3] += a0 * wv.w;
        acc[1][0] += a1 * wv.x; acc[1][1] += a1 * wv.y; acc[1][2] += a1 * wv.z; acc[1][3] += a1 * wv.w;
        acc[2][0] += a2 * wv.x; acc[2][1] += a2 * wv.y; acc[2][2] += a2 * wv.z; acc[2][3] += a2 * wv.w;
        acc[3][0] += a3 * wv.x; acc[3][1] += a3 * wv.y; acc[3][2] += a3 * wv.z; acc[3][3] += a3 * wv.w;
    }
}

__global__ __launch_bounds__(512, 2)
void edge_fused_kernel(const int* __restrict__ esrc, const int* __restrict__ edst,
                       const float* __restrict__ eattr, const float* __restrict__ escal,
                       const float* __restrict__ W1, const float* __restrict__ b1,
                       const float* __restrict__ W2, const float* __restrict__ b2,
                       const float* __restrict__ W3, const float* __restrict__ b3,
                       const float* __restrict__ Wkv, const float* __restrict__ bkv,
                       const float* __restrict__ qbuf, const float* __restrict__ msrc,
                       const float* __restrict__ mdst,
                       float* __restrict__ num, float* __restrict__ den)
{
    // 30400 floats = 121.6 KB static LDS (1 block/CU, 8 waves)
    __shared__ __align__(16) float smem[30400];
    float* sW1   = smem;                 // 4096
    float* sW2   = smem + 4096;          // 4096
    float* sW3   = smem + 8192;          // 4096
    float* sBufA = smem + 12288;         // 128*68 = 8704 (es / h2 / later Wkv)
    float* sBufB = smem + 20992;         // 8704 (h1 / tp)
    float* sb1   = smem + 29696;
    float* sb2   = smem + 29760;
    float* sb3   = smem + 29824;
    float* sbkv  = smem + 29888;         // 128
    int*   s_src = (int*)(smem + 30016); // 128
    int*   s_dst = (int*)(smem + 30144); // 128
    float* s_ea  = smem + 30272;         // 128

    const int t    = threadIdx.x;
    const int base = blockIdx.x * 128;

    // stage MLP weights + biases + edge metadata
    for (int i4 = t; i4 < 1024; i4 += 512) {
        ((float4*)sW1)[i4] = ((const float4*)W1)[i4];
        ((float4*)sW2)[i4] = ((const float4*)W2)[i4];
        ((float4*)sW3)[i4] = ((const float4*)W3)[i4];
    }
    if (t < 64)                { sb1[t] = b1[t]; sb2[t] = b2[t]; sb3[t] = b3[t]; }
    if (t >= 64  && t < 192)   sbkv[t - 64] = bkv[t - 64];
    if (t >= 192 && t < 320)   { s_src[t - 192] = esrc[base + t - 192];
                                 s_dst[t - 192] = edst[base + t - 192]; }
    if (t >= 320 && t < 448)   s_ea[t - 320] = eattr[base + t - 320];

    // stage edge_scalars tile -> bufA
    {
        int e = t >> 4;
        const int c4 = (t & 15) << 2;
#pragma unroll
        for (int p = 0; p < 4; ++p, e += 32) {
            const float4 g = *(const float4*)&escal[(size_t)(base + e) * 64 + c4];
            *(float4*)&sBufA[e * 68 + c4] = g;
        }
    }
    __syncthreads();

    const int te = t >> 4;     // 0..31 -> 4 edges each
    const int tj = t & 15;     // 0..15 -> 4 cols each
    const int j0 = tj << 2;
    const int e0 = te << 2;

    float acc[4][4];

    // ---- Layer 1: silu(es@W1+b1) -> bufB
    gemm_tile64(sBufA, sW1, e0, j0, acc);
#pragma unroll
    for (int i = 0; i < 4; ++i) {
        float4 o;
        float v0 = acc[i][0] + sb1[j0 + 0]; o.x = v0 / (1.f + __expf(-v0));
        float v1 = acc[i][1] + sb1[j0 + 1]; o.y = v1 / (1.f + __expf(-v1));
        float v2 = acc[i][2] + sb1[j0 + 2]; o.z = v2 / (1.f + __expf(-v2));
        float v3 = acc[i][3] + sb1[j0 + 3]; o.w = v3 / (1.f + __expf(-v3));
        *(float4*)&sBufB[(e0 + i) * 68 + j0] = o;
    }
    __syncthreads();

    // ---- Layer 2: silu(h1@W2+b2) -> bufA
    gemm_tile64(sBufB, sW2, e0, j0, acc);
#pragma unroll
    for (int i = 0; i < 4; ++i) {
        float4 o;
        float v0 = acc[i][0] + sb2[j0 + 0]; o.x = v0 / (1.f + __expf(-v0));
        float v1 = acc[i][1] + sb2[j0 + 1]; o.y = v1 / (1.f + __expf(-v1));
        float v2 = acc[i][2] + sb2[j0 + 2]; o.z = v2 / (1.f + __expf(-v2));
        float v3 = acc[i][3] + sb2[j0 + 3]; o.w = v3 / (1.f + __expf(-v3));
        *(float4*)&sBufA[(e0 + i) * 68 + j0] = o;
    }
    __syncthreads();

    // ---- Layer 3: w = h2@W3+b3; tp = (msrc[src]+mdst[dst])*ea*w -> bufB
    gemm_tile64(sBufA, sW3, e0, j0, acc);
#pragma unroll
    for (int i = 0; i < 4; ++i) {
        const int e  = e0 + i;
        const int gs = s_src[e];
        const int gd = s_dst[e];
        const float ea = s_ea[e];
        const float4 a4 = *(const float4*)&msrc[(size_t)gs * 64 + j0];
        const float4 b4 = *(const float4*)&mdst[(size_t)gd * 64 + j0];
        float4 tp;
        tp.x = (a4.x + b4.x) * ea * (acc[i][0] + sb3[j0 + 0]);
        tp.y = (a4.y + b4.y) * ea * (acc[i][1] + sb3[j0 + 1]);
        tp.z = (a4.z + b4.z) * ea * (acc[i][2] + sb3[j0 + 2]);
        tp.w = (a4.w + b4.w) * ea * (acc[i][3] + sb3[j0 + 3]);
        *(float4*)&sBufB[e * 68 + j0] = tp;
    }
    __syncthreads();

    // ---- stage Wkv into bufA region (bufA dead now)
    for (int i4 = t; i4 < 2048; i4 += 512)
        ((float4*)sBufA)[i4] = ((const float4*)Wkv)[i4];
    __syncthreads();
    const float* sWkv = sBufA;

    // ---- kv2 = tp@Wkv: k part (cols 0..63) + v part (cols 64..127)
    float acc2[4][8];
#pragma unroll
    for (int i = 0; i < 4; ++i)
#pragma unroll
        for (int c = 0; c < 8; ++c) acc2[i][c] = 0.f;
#pragma unroll 8
    for (int k = 0; k < 64; ++k) {
        const float4 wk = *(const float4*)&sWkv[k * 128 + j0];
        const float4 wv = *(const float4*)&sWkv[k * 128 + 64 + j0];
        const float a0 = sBufB[(e0 + 0) * 68 + k];
        const float a1 = sBufB[(e0 + 1) * 68 + k];
        const float a2 = sBufB[(e0 + 2) * 68 + k];
        const float a3 = sBufB[(e0 + 3) * 68 + k];
        acc2[0][0] += a0 * wk.x; acc2[0][1] += a0 * wk.y; acc2[0][2] += a0 * wk.z; acc2[0][3] += a0 * wk.w;
        acc2[1][0] += a1 * wk.x; acc2[1][1] += a1 * wk.y; acc2[1][2] += a1 * wk.z; acc2[1][3] += a1 * wk.w;
        acc2[2][0] += a2 * wk.x; acc2[2][1] += a2 * wk.y; acc2[2][2] += a2 * wk.z; acc2[2][3] += a2 * wk.w;
        acc2[3][0] += a3 * wk.x; acc2[3][1] += a3 * wk.y; acc2[3][2] += a3 * wk.z; acc2[3][3] += a3 * wk.w;
        acc2[0][4] += a0 * wv.x; acc2[0][5] += a0 * wv.y; acc2[0][6] += a0 * wv.z; acc2[0][7] += a0 * wv.w;
        acc2[1][4] += a1 * wv.x; acc2[1][5] += a1 * wv.y; acc2[1][6] += a1 * wv.z; acc2[1][7] += a1 * wv.w;
        acc2[2][4] += a2 * wv.x; acc2[2][5] += a2 * wv.y; acc2[2][6] += a2 * wv.z; acc2[2][7] += a2 * wv.w;
        acc2[3][4] += a3 * wv.x; acc2[3][5] += a3 * wv.y; acc2[3][6] += a3 * wv.z; acc2[3][7] += a3 * wv.w;
    }

    // ---- alpha (4-lane reduce within head), exp, atomics
    const int h = tj >> 2;
#pragma unroll
    for (int i = 0; i < 4; ++i) {
        const int e  = e0 + i;
        const int gd = s_dst[e];
        const float4 qv = *(const float4*)&qbuf[(size_t)gd * 64 + j0];
        float s = (acc2[i][0] + sbkv[j0 + 0]) * qv.x
                + (acc2[i][1] + sbkv[j0 + 1]) * qv.y
                + (acc2[i][2] + sbkv[j0 + 2]) * qv.z
                + (acc2[i][3] + sbkv[j0 + 3]) * qv.w;
        s += __shfl_xor(s, 1);
        s += __shfl_xor(s, 2);
        const float ex = __expf(s);
        float* np = &num[(size_t)gd * 64 + j0];
        atomicAdd(np + 0, ex * (acc2[i][4] + sbkv[64 + j0 + 0]));
        atomicAdd(np + 1, ex * (acc2[i][5] + sbkv[64 + j0 + 1]));
        atomicAdd(np + 2, ex * (acc2[i][6] + sbkv[64 + j0 + 2]));
        atomicAdd(np + 3, ex * (acc2[i][7] + sbkv[64 + j0 + 3]));
        if ((tj & 3) == 0) atomicAdd(&den[(size_t)gd * 4 + h], ex);
    }
}

// ---------------------------------------------------------------------------
// Kernel C: out = (num / (den+1e-16)) @ W_proj + b_proj  (64-node tiles)
// ---------------------------------------------------------------------------
__global__ __launch_bounds__(256)
void final_proj_kernel(const float* __restrict__ num, const float* __restrict__ den,
                       const float* __restrict__ Wp, const float* __restrict__ bp,
                       float* __restrict__ out, int N)
{
    __shared__ __align__(16) float sW[64 * 64];
    __shared__ float sb[64];
    __shared__ __align__(16) float at[64][68];

    const int t = threadIdx.x;
    for (int i4 = t; i4 < 1024; i4 += 256)
        ((float4*)sW)[i4] = ((const float4*)Wp)[i4];
    if (t < 64) sb[t] = bp[t];

    const int nbase = blockIdx.x * 64;
    for (int idx = t; idx < 1024; idx += 256) {         // 64 rows x 16 float4
        const int n  = idx >> 4;
        const int c4 = (idx & 15) * 4;
        const int gn = nbase + n;
        float4 g = make_float4(0.f, 0.f, 0.f, 0.f);
        if (gn < N) {
            const float4 nm = *(const float4*)&num[(size_t)gn * 64 + c4];
            const float inv = 1.0f / (den[(size_t)gn * 4 + (c4 >> 4)] + 1e-16f);
            g = make_float4(nm.x * inv, nm.y * inv, nm.z * inv, nm.w * inv);
        }
        *(float4*)&at[n][c4] = g;
    }
    __syncthreads();

    const int te = t >> 4, tj = t & 15;
    const int j0 = tj * 4, e0 = te * 4;

    float acc[4][4];
#pragma unroll
    for (int i = 0; i < 4; ++i)
#pragma unroll
        for (int c = 0; c < 4; ++c) acc[i][c] = 0.f;

#pragma unroll 16
    for (int k = 0; k < 64; ++k) {
        const float4 wv = *(const float4*)&sW[k * 64 + j0];
        const float a0 = at[e0 + 0][k];
        const float a1 = at[e0 + 1][k];
        const float a2 = at[e0 + 2][k];
        const float a3 = at[e0 + 3][k];
        acc[0][0] += a0 * wv.x; acc[0][1] += a0 * wv.y; acc[0][2] += a0 * wv.z; acc[0][3] += a0 * wv.w;
        acc[1][0] += a1 * wv.x; acc[1][1] += a1 * wv.y; acc[1][2] += a1 * wv.z; acc[1][3] += a1 * wv.w;
        acc[2][0] += a2 * wv.x; acc[2][1] += a2 * wv.y; acc[2][2] += a2 * wv.z; acc[2][3] += a2 * wv.w;
        acc[3][0] += a3 * wv.x; acc[3][1] += a3 * wv.y; acc[3][2] += a3 * wv.z; acc[3][3] += a3 * wv.w;
    }

#pragma unroll
    for (int i = 0; i < 4; ++i) {
        const int gn = nbase + e0 + i;
        if (gn >= N) continue;
        float4 o;
        o.x = acc[i][0] + sb[j0 + 0];
        o.y = acc[i][1] + sb[j0 + 1];
        o.z = acc[i][2] + sb[j0 + 2];
        o.w = acc[i][3] + sb[j0 + 3];
        *(float4*)&out[(size_t)gn * 64 + j0] = o;
    }
}

// ---------------------------------------------------------------------------
extern "C" void kernel_launch(void* const* d_in, const int* in_sizes, int n_in,
                              void* d_out, int out_size, void* d_ws, size_t ws_size,
                              hipStream_t stream)
{
    const float* node_input = (const float*)d_in[0];
    const int*   edge_src   = (const int*)  d_in[2];
    const int*   edge_dst   = (const int*)  d_in[3];
    const float* edge_attr  = (const float*)d_in[4];
    const float* edge_scal  = (const float*)d_in[5];
    const float* Wq    = (const float*)d_in[7];
    const float* bq    = (const float*)d_in[8];
    const float* W_src = (const float*)d_in[9];
    const float* b_src = (const float*)d_in[10];
    const float* W_dst = (const float*)d_in[11];
    const float* W_fc1 = (const float*)d_in[12];
    const float* b_fc1 = (const float*)d_in[13];
    const float* W_fc2 = (const float*)d_in[14];
    const float* b_fc2 = (const float*)d_in[15];
    const float* W_fc3 = (const float*)d_in[16];
    const float* b_fc3 = (const float*)d_in[17];
    const float* W_kv  = (const float*)d_in[18];
    const float* b_kv  = (const float*)d_in[19];
    const float* W_proj = (const float*)d_in[20];
    const float* b_proj = (const float*)d_in[21];

    const int N = in_sizes[0] / 64;    // 50000
    const int E = in_sizes[2];         // 800000

    float* ws    = (float*)d_ws;
    float* q_buf = ws;                        // N*64
    float* msrc  = ws + (size_t)N * 64;       // N*64
    float* mdst  = ws + (size_t)N * 128;      // N*64
    float* num   = ws + (size_t)N * 192;      // N*64
    float* den   = ws + (size_t)N * 256;      // N*4

    // zero the accumulators (ws is re-poisoned before every timed launch)
    hipMemsetAsync(num, 0, (size_t)N * 68 * sizeof(float), stream);

    // node-side linears
    {
        dim3 grid((N + 31) / 32);
        node_linear_kernel<<<grid, 384, 0, stream>>>(node_input, Wq, bq, W_src, b_src, W_dst,
                                                     q_buf, msrc, mdst, N);
    }
    // fused edge chain + softmax-numerator atomics
    {
        dim3 grid(E / 128);
        edge_fused_kernel<<<grid, 512, 0, stream>>>(edge_src, edge_dst, edge_attr, edge_scal,
                                                    W_fc1, b_fc1, W_fc2, b_fc2, W_fc3, b_fc3,
                                                    W_kv, b_kv, q_buf, msrc, mdst, num, den);
    }
    // normalize + output projection
    {
        dim3 grid((N + 63) / 64);
        final_proj_kernel<<<grid, 256, 0, stream>>>(num, den, W_proj, b_proj, (float*)d_out, N);
    }
}

// Round 5
// 730.241 us; speedup vs baseline: 1.6619x; 1.6619x over previous
//
#include <hip/hip_runtime.h>
#include <hip/hip_bf16.h>

// N_NODES=50000, N_EDGES=800000, C_IN=64, N_HEADS=4, HEAD_DIM=16, FC=64
// Edge tile: 128 edges/block, 512 threads (8 waves), bf16 MFMA chain.

typedef __attribute__((ext_vector_type(8))) short    bf16x8;
typedef __attribute__((ext_vector_type(4))) float    f32x4;
typedef __attribute__((ext_vector_type(4))) unsigned short ushort4v;

__device__ __forceinline__ unsigned short f2bf(float x) {
    union { float f; unsigned u; } v; v.f = x;
    unsigned r = v.u + 0x7fffu + ((v.u >> 16) & 1u);   // round-to-nearest-even
    return (unsigned short)(r >> 16);
}

// swizzled ushort index for a [*][64]-bf16 LDS tile (T2 XOR swizzle)
__device__ __forceinline__ int swz(int row, int k) {
    return row * 64 + (k ^ ((row & 7) << 3));
}

// MFMA fragment load: 8 contiguous bf16 at (row|n, k = kk*32 + lhi*8)
__device__ __forceinline__ bf16x8 ldfrag(const unsigned short* buf, int rn, int kk, int lhi) {
    return *(const bf16x8*)(buf + swz(rn, kk * 32 + lhi * 8));
}

// ---------------------------------------------------------------------------
// Kernel A: node-side linears (unchanged from R1).
// ---------------------------------------------------------------------------
__global__ __launch_bounds__(384)
void node_linear_kernel(const float* __restrict__ x,
                        const float* __restrict__ Wq,   const float* __restrict__ bq,
                        const float* __restrict__ Wsrc, const float* __restrict__ bsrc,
                        const float* __restrict__ Wdst,
                        float* __restrict__ qout, float* __restrict__ msout,
                        float* __restrict__ mdout, int N)
{
    __shared__ __align__(16) float sW[64 * 192];
    __shared__ float sb[192];
    __shared__ __align__(16) float xs[32][68];

    const int t = threadIdx.x;
    for (int idx4 = t; idx4 < 3072; idx4 += 384) {
        const int k  = idx4 / 48;
        const int j4 = idx4 % 48;
        const float4* src = (j4 < 16) ? (const float4*)&Wq  [k * 64 + j4 * 4]
                         : (j4 < 32) ? (const float4*)&Wsrc[k * 64 + (j4 - 16) * 4]
                                     : (const float4*)&Wdst[k * 64 + (j4 - 32) * 4];
        ((float4*)sW)[idx4] = *src;
    }
    if (t < 192) sb[t] = (t < 64) ? bq[t] : (t < 128) ? bsrc[t - 64] : 0.0f;

    const int nbase = blockIdx.x * 32;
    for (int idx = t; idx < 512; idx += 384) {
        const int n  = idx >> 4;
        const int c4 = (idx & 15) * 4;
        const int gn = nbase + n;
        float4 g = make_float4(0.f, 0.f, 0.f, 0.f);
        if (gn < N) g = *(const float4*)&x[(size_t)gn * 64 + c4];
        *(float4*)&xs[n][c4] = g;
    }
    __syncthreads();

    const int te = t / 48, tj = t % 48;
    const int j0 = tj * 4, e0 = te * 4;

    float acc[4][4];
#pragma unroll
    for (int i = 0; i < 4; ++i)
#pragma unroll
        for (int c = 0; c < 4; ++c) acc[i][c] = 0.f;

#pragma unroll 16
    for (int k = 0; k < 64; ++k) {
        const float4 wv = *(const float4*)&sW[k * 192 + j0];
        const float a0 = xs[e0 + 0][k], a1 = xs[e0 + 1][k];
        const float a2 = xs[e0 + 2][k], a3 = xs[e0 + 3][k];
        acc[0][0] += a0 * wv.x; acc[0][1] += a0 * wv.y; acc[0][2] += a0 * wv.z; acc[0][3] += a0 * wv.w;
        acc[1][0] += a1 * wv.x; acc[1][1] += a1 * wv.y; acc[1][2] += a1 * wv.z; acc[1][3] += a1 * wv.w;
        acc[2][0] += a2 * wv.x; acc[2][1] += a2 * wv.y; acc[2][2] += a2 * wv.z; acc[2][3] += a2 * wv.w;
        acc[3][0] += a3 * wv.x; acc[3][1] += a3 * wv.y; acc[3][2] += a3 * wv.z; acc[3][3] += a3 * wv.w;
    }

#pragma unroll
    for (int i = 0; i < 4; ++i) {
        const int gn = nbase + e0 + i;
        if (gn >= N) continue;
        float4 o;
        o.x = acc[i][0] + sb[j0 + 0];
        o.y = acc[i][1] + sb[j0 + 1];
        o.z = acc[i][2] + sb[j0 + 2];
        o.w = acc[i][3] + sb[j0 + 3];
        if (j0 < 64) {
            o.x *= 0.25f; o.y *= 0.25f; o.z *= 0.25f; o.w *= 0.25f;
            *(float4*)&qout[(size_t)gn * 64 + j0] = o;
        } else if (j0 < 128) {
            *(float4*)&msout[(size_t)gn * 64 + (j0 - 64)] = o;
        } else {
            *(float4*)&mdout[(size_t)gn * 64 + (j0 - 128)] = o;
        }
    }
}

// ---------------------------------------------------------------------------
// Kernel B (MFMA): fused per-edge chain.
// Per block: 128 edges. Wave w owns edge-rows [16w,16w+16).
// MFMA 16x16x32 bf16: A row = lane&15, k = kk*32+(lane>>4)*8+j (b128 frag)
//                     B  n  = lane&15, same k            (weights transposed)
//                     D col = lane&15, row = (lane>>4)*4 + reg
// ---------------------------------------------------------------------------
__global__ __launch_bounds__(512, 4)
void edge_fused_mfma(const int* __restrict__ esrc, const int* __restrict__ edst,
                     const float* __restrict__ eattr, const float* __restrict__ escal,
                     const float* __restrict__ W1, const float* __restrict__ b1,
                     const float* __restrict__ W2, const float* __restrict__ b2,
                     const float* __restrict__ W3, const float* __restrict__ b3,
                     const float* __restrict__ Wkv, const float* __restrict__ bkv,
                     const float* __restrict__ qbuf, const float* __restrict__ msrc,
                     const float* __restrict__ mdst,
                     float* __restrict__ num, float* __restrict__ den)
{
    __shared__ __align__(16) unsigned short sh[36864];  // 73728 B
    unsigned short* sW1t  = sh;           // [64][64] bf16, transposed+swz
    unsigned short* sW2t  = sh + 4096;
    unsigned short* sW3t  = sh + 8192;
    unsigned short* sWkvt = sh + 12288;   // [128][64]
    unsigned short* sA0   = sh + 20480;   // [128 edges][64] act ping
    unsigned short* sA1   = sh + 28672;   // act pong
    __shared__ float sB1[64], sB2[64], sB3[64], sBkv[128], sEa[128];
    __shared__ int   sSrc[128], sDst[128];

    const int t    = threadIdx.x;
    const int base = blockIdx.x * 128;
    const int lane = t & 63;
    const int wave = t >> 6;
    const int l15  = lane & 15;
    const int lhi  = lane >> 4;          // 0..3
    const int rowBase = wave * 16;

    // ---- stage weights (transpose to [n][k], bf16, swizzled) ----
    for (int idx = t; idx < 4096; idx += 512) {
        const int k = idx >> 6, n = idx & 63;
        const int d = swz(n, k);
        sW1t[d] = f2bf(W1[idx]);
        sW2t[d] = f2bf(W2[idx]);
        sW3t[d] = f2bf(W3[idx]);
    }
    for (int idx = t; idx < 8192; idx += 512) {
        const int k = idx >> 7, n = idx & 127;
        sWkvt[swz(n, k)] = f2bf(Wkv[idx]);
    }
    // ---- stage edge_scalars tile (bf16, swizzled) ----
    for (int i4 = t; i4 < 2048; i4 += 512) {
        const int e = i4 >> 4, k4 = (i4 & 15) << 2;
        const float4 g = *(const float4*)&escal[(size_t)(base + e) * 64 + k4];
        ushort4v p = { f2bf(g.x), f2bf(g.y), f2bf(g.z), f2bf(g.w) };
        *(ushort4v*)&sA0[swz(e, k4)] = p;
    }
    // ---- biases + metadata ----
    if (t < 64)              { sB1[t] = b1[t]; sB2[t] = b2[t]; sB3[t] = b3[t]; }
    if (t >= 64  && t < 192) sBkv[t - 64] = bkv[t - 64];
    if (t >= 192 && t < 320) {
        const int e = t - 192;
        sSrc[e] = esrc[base + e];
        sDst[e] = edst[base + e];
        sEa[e]  = eattr[base + e];
    }
    __syncthreads();

    // ================= Layer 1: silu(es@W1+b1) : sA0 -> sA1 =================
    {
        f32x4 acc[4] = {{0,0,0,0},{0,0,0,0},{0,0,0,0},{0,0,0,0}};
#pragma unroll
        for (int kk = 0; kk < 2; ++kk) {
            const bf16x8 a = ldfrag(sA0, rowBase + l15, kk, lhi);
#pragma unroll
            for (int c = 0; c < 4; ++c) {
                const bf16x8 b = ldfrag(sW1t, c * 16 + l15, kk, lhi);
                acc[c] = __builtin_amdgcn_mfma_f32_16x16x32_bf16(a, b, acc[c], 0, 0, 0);
            }
        }
#pragma unroll
        for (int c = 0; c < 4; ++c)
#pragma unroll
            for (int r = 0; r < 4; ++r) {
                const int row = rowBase + lhi * 4 + r;
                const int col = c * 16 + l15;
                const float v = acc[c][r] + sB1[col];
                sA1[swz(row, col)] = f2bf(v / (1.f + __expf(-v)));
            }
    }
    __syncthreads();

    // ================= Layer 2: silu(h1@W2+b2) : sA1 -> sA0 =================
    {
        f32x4 acc[4] = {{0,0,0,0},{0,0,0,0},{0,0,0,0},{0,0,0,0}};
#pragma unroll
        for (int kk = 0; kk < 2; ++kk) {
            const bf16x8 a = ldfrag(sA1, rowBase + l15, kk, lhi);
#pragma unroll
            for (int c = 0; c < 4; ++c) {
                const bf16x8 b = ldfrag(sW2t, c * 16 + l15, kk, lhi);
                acc[c] = __builtin_amdgcn_mfma_f32_16x16x32_bf16(a, b, acc[c], 0, 0, 0);
            }
        }
#pragma unroll
        for (int c = 0; c < 4; ++c)
#pragma unroll
            for (int r = 0; r < 4; ++r) {
                const int row = rowBase + lhi * 4 + r;
                const int col = c * 16 + l15;
                const float v = acc[c][r] + sB2[col];
                sA0[swz(row, col)] = f2bf(v / (1.f + __expf(-v)));
            }
    }
    __syncthreads();

    // ===== Layer 3 + tp: w = h2@W3+b3; tp=(msrc[s]+mdst[d])*ea*w : sA0 -> sA1
    {
        f32x4 acc[4] = {{0,0,0,0},{0,0,0,0},{0,0,0,0},{0,0,0,0}};
#pragma unroll
        for (int kk = 0; kk < 2; ++kk) {
            const bf16x8 a = ldfrag(sA0, rowBase + l15, kk, lhi);
#pragma unroll
            for (int c = 0; c < 4; ++c) {
                const bf16x8 b = ldfrag(sW3t, c * 16 + l15, kk, lhi);
                acc[c] = __builtin_amdgcn_mfma_f32_16x16x32_bf16(a, b, acc[c], 0, 0, 0);
            }
        }
        // independent gathers first (compiler pipelines the 32 dword loads)
        float ms[4][4], md[4][4];
#pragma unroll
        for (int c = 0; c < 4; ++c)
#pragma unroll
            for (int r = 0; r < 4; ++r) {
                const int row = rowBase + lhi * 4 + r;
                const int col = c * 16 + l15;
                ms[c][r] = msrc[(size_t)sSrc[row] * 64 + col];
                md[c][r] = mdst[(size_t)sDst[row] * 64 + col];
            }
#pragma unroll
        for (int c = 0; c < 4; ++c)
#pragma unroll
            for (int r = 0; r < 4; ++r) {
                const int row = rowBase + lhi * 4 + r;
                const int col = c * 16 + l15;
                const float w  = acc[c][r] + sB3[col];
                const float tp = (ms[c][r] + md[c][r]) * sEa[row] * w;
                sA1[swz(row, col)] = f2bf(tp);
            }
    }
    __syncthreads();

    // ================= kv2 = tp@Wkv (+bkv): k cols 0..63, v cols 64..127 ====
    f32x4 acc2[8] = {{0,0,0,0},{0,0,0,0},{0,0,0,0},{0,0,0,0},
                     {0,0,0,0},{0,0,0,0},{0,0,0,0},{0,0,0,0}};
#pragma unroll
    for (int kk = 0; kk < 2; ++kk) {
        const bf16x8 a = ldfrag(sA1, rowBase + l15, kk, lhi);
#pragma unroll
        for (int c = 0; c < 8; ++c) {
            const bf16x8 b = ldfrag(sWkvt, c * 16 + l15, kk, lhi);
            acc2[c] = __builtin_amdgcn_mfma_f32_16x16x32_bf16(a, b, acc2[c], 0, 0, 0);
        }
    }

    // ================= alpha, exp, atomics ==================================
    // D frag: lane holds (row = rowBase+lhi*4+r, col = c*16+l15).  Head = c.
    int   gds[4];
    float qreg[4][4];
#pragma unroll
    for (int r = 0; r < 4; ++r) gds[r] = sDst[rowBase + lhi * 4 + r];
#pragma unroll
    for (int h = 0; h < 4; ++h)
#pragma unroll
        for (int r = 0; r < 4; ++r)
            qreg[h][r] = qbuf[(size_t)gds[r] * 64 + h * 16 + l15];

    float ex[4][4];
#pragma unroll
    for (int h = 0; h < 4; ++h)
#pragma unroll
        for (int r = 0; r < 4; ++r) {
            float s = (acc2[h][r] + sBkv[h * 16 + l15]) * qreg[h][r];
            s += __shfl_xor(s, 1);
            s += __shfl_xor(s, 2);
            s += __shfl_xor(s, 4);
            s += __shfl_xor(s, 8);
            const float e = __expf(s);
            ex[h][r] = e;
            if (l15 == h * 4 + r) atomicAdd(&den[(size_t)gds[r] * 4 + h], e);
        }

#pragma unroll
    for (int vt = 0; vt < 4; ++vt)
#pragma unroll
        for (int r = 0; r < 4; ++r) {
            const float vv = acc2[4 + vt][r] + sBkv[64 + vt * 16 + l15];
            atomicAdd(&num[(size_t)gds[r] * 64 + vt * 16 + l15], ex[vt][r] * vv);
        }
}

// ---------------------------------------------------------------------------
// Kernel C: out = (num/(den+1e-16)) @ W_proj + b_proj  (unchanged from R1)
// ---------------------------------------------------------------------------
__global__ __launch_bounds__(256)
void final_proj_kernel(const float* __restrict__ num, const float* __restrict__ den,
                       const float* __restrict__ Wp, const float* __restrict__ bp,
                       float* __restrict__ out, int N)
{
    __shared__ __align__(16) float sW[64 * 64];
    __shared__ float sb[64];
    __shared__ __align__(16) float at[64][68];

    const int t = threadIdx.x;
    for (int i4 = t; i4 < 1024; i4 += 256)
        ((float4*)sW)[i4] = ((const float4*)Wp)[i4];
    if (t < 64) sb[t] = bp[t];

    const int nbase = blockIdx.x * 64;
    for (int idx = t; idx < 1024; idx += 256) {
        const int n  = idx >> 4;
        const int c4 = (idx & 15) * 4;
        const int gn = nbase + n;
        float4 g = make_float4(0.f, 0.f, 0.f, 0.f);
        if (gn < N) {
            const float4 nm = *(const float4*)&num[(size_t)gn * 64 + c4];
            const float inv = 1.0f / (den[(size_t)gn * 4 + (c4 >> 4)] + 1e-16f);
            g = make_float4(nm.x * inv, nm.y * inv, nm.z * inv, nm.w * inv);
        }
        *(float4*)&at[n][c4] = g;
    }
    __syncthreads();

    const int te = t >> 4, tj = t & 15;
    const int j0 = tj * 4, e0 = te * 4;

    float acc[4][4];
#pragma unroll
    for (int i = 0; i < 4; ++i)
#pragma unroll
        for (int c = 0; c < 4; ++c) acc[i][c] = 0.f;

#pragma unroll 16
    for (int k = 0; k < 64; ++k) {
        const float4 wv = *(const float4*)&sW[k * 64 + j0];
        const float a0 = at[e0 + 0][k], a1 = at[e0 + 1][k];
        const float a2 = at[e0 + 2][k], a3 = at[e0 + 3][k];
        acc[0][0] += a0 * wv.x; acc[0][1] += a0 * wv.y; acc[0][2] += a0 * wv.z; acc[0][3] += a0 * wv.w;
        acc[1][0] += a1 * wv.x; acc[1][1] += a1 * wv.y; acc[1][2] += a1 * wv.z; acc[1][3] += a1 * wv.w;
        acc[2][0] += a2 * wv.x; acc[2][1] += a2 * wv.y; acc[2][2] += a2 * wv.z; acc[2][3] += a2 * wv.w;
        acc[3][0] += a3 * wv.x; acc[3][1] += a3 * wv.y; acc[3][2] += a3 * wv.z; acc[3][3] += a3 * wv.w;
    }

#pragma unroll
    for (int i = 0; i < 4; ++i) {
        const int gn = nbase + e0 + i;
        if (gn >= N) continue;
        float4 o;
        o.x = acc[i][0] + sb[j0 + 0];
        o.y = acc[i][1] + sb[j0 + 1];
        o.z = acc[i][2] + sb[j0 + 2];
        o.w = acc[i][3] + sb[j0 + 3];
        *(float4*)&out[(size_t)gn * 64 + j0] = o;
    }
}

// ---------------------------------------------------------------------------
extern "C" void kernel_launch(void* const* d_in, const int* in_sizes, int n_in,
                              void* d_out, int out_size, void* d_ws, size_t ws_size,
                              hipStream_t stream)
{
    const float* node_input = (const float*)d_in[0];
    const int*   edge_src   = (const int*)  d_in[2];
    const int*   edge_dst   = (const int*)  d_in[3];
    const float* edge_attr  = (const float*)d_in[4];
    const float* edge_scal  = (const float*)d_in[5];
    const float* Wq    = (const float*)d_in[7];
    const float* bq    = (const float*)d_in[8];
    const float* W_src = (const float*)d_in[9];
    const float* b_src = (const float*)d_in[10];
    const float* W_dst = (const float*)d_in[11];
    const float* W_fc1 = (const float*)d_in[12];
    const float* b_fc1 = (const float*)d_in[13];
    const float* W_fc2 = (const float*)d_in[14];
    const float* b_fc2 = (const float*)d_in[15];
    const float* W_fc3 = (const float*)d_in[16];
    const float* b_fc3 = (const float*)d_in[17];
    const float* W_kv  = (const float*)d_in[18];
    const float* b_kv  = (const float*)d_in[19];
    const float* W_proj = (const float*)d_in[20];
    const float* b_proj = (const float*)d_in[21];

    const int N = in_sizes[0] / 64;    // 50000
    const int E = in_sizes[2];         // 800000

    float* ws    = (float*)d_ws;
    float* q_buf = ws;                        // N*64
    float* msrc  = ws + (size_t)N * 64;       // N*64
    float* mdst  = ws + (size_t)N * 128;      // N*64
    float* num   = ws + (size_t)N * 192;      // N*64
    float* den   = ws + (size_t)N * 256;      // N*4

    hipMemsetAsync(num, 0, (size_t)N * 68 * sizeof(float), stream);

    {
        dim3 grid((N + 31) / 32);
        node_linear_kernel<<<grid, 384, 0, stream>>>(node_input, Wq, bq, W_src, b_src, W_dst,
                                                     q_buf, msrc, mdst, N);
    }
    {
        dim3 grid(E / 128);
        edge_fused_mfma<<<grid, 512, 0, stream>>>(edge_src, edge_dst, edge_attr, edge_scal,
                                                  W_fc1, b_fc1, W_fc2, b_fc2, W_fc3, b_fc3,
                                                  W_kv, b_kv, q_buf, msrc, mdst, num, den);
    }
    {
        dim3 grid((N + 63) / 64);
        final_proj_kernel<<<grid, 256, 0, stream>>>(num, den, W_proj, b_proj, (float*)d_out, N);
    }
}

// Round 7
// 672.176 us; speedup vs baseline: 1.8055x; 1.0864x over previous
//
#include <hip/hip_runtime.h>
#include <hip/hip_bf16.h>

// N_NODES=50000, N_EDGES=800000, C_IN=64, N_HEADS=4, HEAD_DIM=16, FC=64
// Edge tile: 128 edges, 512 threads (8 waves), bf16 MFMA chain,
// persistent blocks + pre-swizzled bf16 weights in d_ws.

typedef __attribute__((ext_vector_type(8))) short    bf16x8;
typedef __attribute__((ext_vector_type(4))) float    f32x4;
typedef __attribute__((ext_vector_type(4))) unsigned short ushort4v;

__device__ __forceinline__ unsigned short f2bf(float x) {
    union { float f; unsigned u; } v; v.f = x;
    unsigned r = v.u + 0x7fffu + ((v.u >> 16) & 1u);   // round-to-nearest-even
    return (unsigned short)(r >> 16);
}

// swizzled ushort index for a [*][64]-bf16 LDS tile (T2 XOR swizzle)
__device__ __forceinline__ int swz(int row, int k) {
    return row * 64 + (k ^ ((row & 7) << 3));
}

// MFMA fragment load: 8 contiguous bf16 at (row|n, k = kk*32 + lhi*8)
__device__ __forceinline__ bf16x8 ldfrag(const unsigned short* buf, int rn, int kk, int lhi) {
    return *(const bf16x8*)(buf + swz(rn, kk * 32 + lhi * 8));
}

// ---------------------------------------------------------------------------
// Kernel P: one-time weight conversion to bf16, PRE-SWIZZLED, into d_ws.
// Output layout (ushort): [0,4096) W1t | [4096,8192) W2t | [8192,12288) W3t
//                         [12288,20480) Wkvt.  Linear dest, inverse-swz src.
// ---------------------------------------------------------------------------
__global__ __launch_bounds__(256)
void prep_weights(const float* __restrict__ W1, const float* __restrict__ W2,
                  const float* __restrict__ W3, const float* __restrict__ Wkv,
                  unsigned short* __restrict__ wbf)
{
    const int d = blockIdx.x * 256 + threadIdx.x;      // 0..20479
    if (d < 12288) {
        const int w  = d >> 12;
        const int r  = d & 4095;
        const int n  = r >> 6, kx = r & 63;
        const int k  = kx ^ ((n & 7) << 3);
        const float* W = (w == 0) ? W1 : (w == 1) ? W2 : W3;
        wbf[d] = f2bf(W[k * 64 + n]);
    } else if (d < 20480) {
        const int r  = d - 12288;
        const int n  = r >> 6, kx = r & 63;             // n: 0..127
        const int k  = kx ^ ((n & 7) << 3);
        wbf[d] = f2bf(Wkv[k * 128 + n]);
    }
}

// ---------------------------------------------------------------------------
// Kernel A: node-side linears, persistent (stage [64][192] weights ONCE).
// ---------------------------------------------------------------------------
__global__ __launch_bounds__(384)
void node_linear_kernel(const float* __restrict__ x,
                        const float* __restrict__ Wq,   const float* __restrict__ bq,
                        const float* __restrict__ Wsrc, const float* __restrict__ bsrc,
                        const float* __restrict__ Wdst,
                        float* __restrict__ qout, float* __restrict__ msout,
                        float* __restrict__ mdout, int N, int ntiles)
{
    __shared__ __align__(16) float sW[64 * 192];
    __shared__ float sb[192];
    __shared__ __align__(16) float xs[32][68];

    const int t = threadIdx.x;
    for (int idx4 = t; idx4 < 3072; idx4 += 384) {
        const int k  = idx4 / 48;
        const int j4 = idx4 % 48;
        const float4* src = (j4 < 16) ? (const float4*)&Wq  [k * 64 + j4 * 4]
                         : (j4 < 32) ? (const float4*)&Wsrc[k * 64 + (j4 - 16) * 4]
                                     : (const float4*)&Wdst[k * 64 + (j4 - 32) * 4];
        ((float4*)sW)[idx4] = *src;
    }
    if (t < 192) sb[t] = (t < 64) ? bq[t] : (t < 128) ? bsrc[t - 64] : 0.0f;

    const int te = t / 48, tj = t % 48;
    const int j0 = tj * 4, e0 = te * 4;

    for (int tile = blockIdx.x; tile < ntiles; tile += gridDim.x) {
        const int nbase = tile * 32;
        __syncthreads();                       // weights ready / prev xs consumed
        for (int idx = t; idx < 512; idx += 384) {
            const int n  = idx >> 4;
            const int c4 = (idx & 15) * 4;
            const int gn = nbase + n;
            float4 g = make_float4(0.f, 0.f, 0.f, 0.f);
            if (gn < N) g = *(const float4*)&x[(size_t)gn * 64 + c4];
            *(float4*)&xs[n][c4] = g;
        }
        __syncthreads();

        float acc[4][4];
#pragma unroll
        for (int i = 0; i < 4; ++i)
#pragma unroll
            for (int c = 0; c < 4; ++c) acc[i][c] = 0.f;

#pragma unroll 16
        for (int k = 0; k < 64; ++k) {
            const float4 wv = *(const float4*)&sW[k * 192 + j0];
            const float a0 = xs[e0 + 0][k], a1 = xs[e0 + 1][k];
            const float a2 = xs[e0 + 2][k], a3 = xs[e0 + 3][k];
            acc[0][0] += a0 * wv.x; acc[0][1] += a0 * wv.y; acc[0][2] += a0 * wv.z; acc[0][3] += a0 * wv.w;
            acc[1][0] += a1 * wv.x; acc[1][1] += a1 * wv.y; acc[1][2] += a1 * wv.z; acc[1][3] += a1 * wv.w;
            acc[2][0] += a2 * wv.x; acc[2][1] += a2 * wv.y; acc[2][2] += a2 * wv.z; acc[2][3] += a2 * wv.w;
            acc[3][0] += a3 * wv.x; acc[3][1] += a3 * wv.y; acc[3][2] += a3 * wv.z; acc[3][3] += a3 * wv.w;
        }

#pragma unroll
        for (int i = 0; i < 4; ++i) {
            const int gn = nbase + e0 + i;
            if (gn >= N) continue;
            float4 o;
            o.x = acc[i][0] + sb[j0 + 0];
            o.y = acc[i][1] + sb[j0 + 1];
            o.z = acc[i][2] + sb[j0 + 2];
            o.w = acc[i][3] + sb[j0 + 3];
            if (j0 < 64) {
                o.x *= 0.25f; o.y *= 0.25f; o.z *= 0.25f; o.w *= 0.25f;
                *(float4*)&qout[(size_t)gn * 64 + j0] = o;
            } else if (j0 < 128) {
                *(float4*)&msout[(size_t)gn * 64 + (j0 - 64)] = o;
            } else {
                *(float4*)&mdout[(size_t)gn * 64 + (j0 - 128)] = o;
            }
        }
    }
}

// ---------------------------------------------------------------------------
// Kernel B (MFMA): fused per-edge chain, persistent.
// Weights staged ONCE per block from pre-swizzled bf16 (vector copies).
// ---------------------------------------------------------------------------
__global__ __launch_bounds__(512, 4)
void edge_fused_mfma(const int* __restrict__ esrc, const int* __restrict__ edst,
                     const float* __restrict__ eattr, const float* __restrict__ escal,
                     const unsigned short* __restrict__ wbf,
                     const float* __restrict__ b1, const float* __restrict__ b2,
                     const float* __restrict__ b3, const float* __restrict__ bkv,
                     const float* __restrict__ qbuf, const float* __restrict__ msrc,
                     const float* __restrict__ mdst,
                     float* __restrict__ num, float* __restrict__ den, int ntiles)
{
    __shared__ __align__(16) unsigned short sh[36864];  // 73728 B
    unsigned short* sW1t  = sh;           // [64][64] bf16, transposed+swz
    unsigned short* sW2t  = sh + 4096;
    unsigned short* sW3t  = sh + 8192;
    unsigned short* sWkvt = sh + 12288;   // [128][64]
    unsigned short* sA0   = sh + 20480;   // [128 edges][64] act ping
    unsigned short* sA1   = sh + 28672;   // act pong
    __shared__ float sB1[64], sB2[64], sB3[64], sBkv[128], sEa[128];
    __shared__ int   sSrc[128], sDst[128];

    const int t    = threadIdx.x;
    const int lane = t & 63;
    const int wave = t >> 6;
    const int l15  = lane & 15;
    const int lhi  = lane >> 4;          // 0..3
    const int rowBase = wave * 16;

    // ---- stage ALL weights once: 20480 ushorts = 2560 float4 (5/thread) ----
    for (int i4 = t; i4 < 2560; i4 += 512)
        ((float4*)sh)[i4] = ((const float4*)wbf)[i4];
    if (t < 64)              { sB1[t] = b1[t]; sB2[t] = b2[t]; sB3[t] = b3[t]; }
    if (t >= 64 && t < 192)  sBkv[t - 64] = bkv[t - 64];

    for (int tile = blockIdx.x; tile < ntiles; tile += gridDim.x) {
        const int base = tile * 128;
        __syncthreads();   // weights ready / prev tile's sA1+metadata consumed

        // ---- stage edge_scalars tile (bf16, swizzled) + metadata ----
        {
            int e = t >> 4;
            const int c4 = (t & 15) << 2;
#pragma unroll
            for (int p = 0; p < 4; ++p, e += 32) {
                const float4 g = *(const float4*)&escal[(size_t)(base + e) * 64 + c4];
                ushort4v pk = { f2bf(g.x), f2bf(g.y), f2bf(g.z), f2bf(g.w) };
                *(ushort4v*)&sA0[swz(e, c4)] = pk;
            }
        }
        if (t >= 192 && t < 320) {
            const int e = t - 192;
            sSrc[e] = esrc[base + e];
            sDst[e] = edst[base + e];
            sEa[e]  = eattr[base + e];
        }
        __syncthreads();

        // ================= Layer 1: silu(es@W1+b1) : sA0 -> sA1 =============
        {
            f32x4 acc[4] = {{0,0,0,0},{0,0,0,0},{0,0,0,0},{0,0,0,0}};
#pragma unroll
            for (int kk = 0; kk < 2; ++kk) {
                const bf16x8 a = ldfrag(sA0, rowBase + l15, kk, lhi);
#pragma unroll
                for (int c = 0; c < 4; ++c) {
                    const bf16x8 b = ldfrag(sW1t, c * 16 + l15, kk, lhi);
                    acc[c] = __builtin_amdgcn_mfma_f32_16x16x32_bf16(a, b, acc[c], 0, 0, 0);
                }
            }
#pragma unroll
            for (int c = 0; c < 4; ++c)
#pragma unroll
                for (int r = 0; r < 4; ++r) {
                    const int row = rowBase + lhi * 4 + r;
                    const int col = c * 16 + l15;
                    const float v = acc[c][r] + sB1[col];
                    sA1[swz(row, col)] = f2bf(v / (1.f + __expf(-v)));
                }
        }
        __syncthreads();

        // ================= Layer 2: silu(h1@W2+b2) : sA1 -> sA0 =============
        {
            f32x4 acc[4] = {{0,0,0,0},{0,0,0,0},{0,0,0,0},{0,0,0,0}};
#pragma unroll
            for (int kk = 0; kk < 2; ++kk) {
                const bf16x8 a = ldfrag(sA1, rowBase + l15, kk, lhi);
#pragma unroll
                for (int c = 0; c < 4; ++c) {
                    const bf16x8 b = ldfrag(sW2t, c * 16 + l15, kk, lhi);
                    acc[c] = __builtin_amdgcn_mfma_f32_16x16x32_bf16(a, b, acc[c], 0, 0, 0);
                }
            }
#pragma unroll
            for (int c = 0; c < 4; ++c)
#pragma unroll
                for (int r = 0; r < 4; ++r) {
                    const int row = rowBase + lhi * 4 + r;
                    const int col = c * 16 + l15;
                    const float v = acc[c][r] + sB2[col];
                    sA0[swz(row, col)] = f2bf(v / (1.f + __expf(-v)));
                }
        }
        __syncthreads();

        // ===== Layer 3 + tp: w = h2@W3+b3; tp=(msrc[s]+mdst[d])*ea*w ========
        {
            f32x4 acc[4] = {{0,0,0,0},{0,0,0,0},{0,0,0,0},{0,0,0,0}};
#pragma unroll
            for (int kk = 0; kk < 2; ++kk) {
                const bf16x8 a = ldfrag(sA0, rowBase + l15, kk, lhi);
#pragma unroll
                for (int c = 0; c < 4; ++c) {
                    const bf16x8 b = ldfrag(sW3t, c * 16 + l15, kk, lhi);
                    acc[c] = __builtin_amdgcn_mfma_f32_16x16x32_bf16(a, b, acc[c], 0, 0, 0);
                }
            }
            float ms[4][4], md[4][4];
#pragma unroll
            for (int c = 0; c < 4; ++c)
#pragma unroll
                for (int r = 0; r < 4; ++r) {
                    const int row = rowBase + lhi * 4 + r;
                    const int col = c * 16 + l15;
                    ms[c][r] = msrc[(size_t)sSrc[row] * 64 + col];
                    md[c][r] = mdst[(size_t)sDst[row] * 64 + col];
                }
#pragma unroll
            for (int c = 0; c < 4; ++c)
#pragma unroll
                for (int r = 0; r < 4; ++r) {
                    const int row = rowBase + lhi * 4 + r;
                    const int col = c * 16 + l15;
                    const float w  = acc[c][r] + sB3[col];
                    const float tp = (ms[c][r] + md[c][r]) * sEa[row] * w;
                    sA1[swz(row, col)] = f2bf(tp);
                }
        }
        __syncthreads();

        // ============ kv2 = tp@Wkv (+bkv): k cols 0..63, v cols 64..127 =====
        f32x4 acc2[8] = {{0,0,0,0},{0,0,0,0},{0,0,0,0},{0,0,0,0},
                         {0,0,0,0},{0,0,0,0},{0,0,0,0},{0,0,0,0}};
#pragma unroll
        for (int kk = 0; kk < 2; ++kk) {
            const bf16x8 a = ldfrag(sA1, rowBase + l15, kk, lhi);
#pragma unroll
            for (int c = 0; c < 8; ++c) {
                const bf16x8 b = ldfrag(sWkvt, c * 16 + l15, kk, lhi);
                acc2[c] = __builtin_amdgcn_mfma_f32_16x16x32_bf16(a, b, acc2[c], 0, 0, 0);
            }
        }

        // ================= alpha, exp, atomics ==============================
        int   gds[4];
        float qreg[4][4];
#pragma unroll
        for (int r = 0; r < 4; ++r) gds[r] = sDst[rowBase + lhi * 4 + r];
#pragma unroll
        for (int h = 0; h < 4; ++h)
#pragma unroll
            for (int r = 0; r < 4; ++r)
                qreg[h][r] = qbuf[(size_t)gds[r] * 64 + h * 16 + l15];

        float ex[4][4];
#pragma unroll
        for (int h = 0; h < 4; ++h)
#pragma unroll
            for (int r = 0; r < 4; ++r) {
                float s = (acc2[h][r] + sBkv[h * 16 + l15]) * qreg[h][r];
                s += __shfl_xor(s, 1);
                s += __shfl_xor(s, 2);
                s += __shfl_xor(s, 4);
                s += __shfl_xor(s, 8);
                const float e = __expf(s);
                ex[h][r] = e;
                if (l15 == h * 4 + r) atomicAdd(&den[(size_t)gds[r] * 4 + h], e);
            }

#pragma unroll
        for (int vt = 0; vt < 4; ++vt)
#pragma unroll
            for (int r = 0; r < 4; ++r) {
                const float vv = acc2[4 + vt][r] + sBkv[64 + vt * 16 + l15];
                atomicAdd(&num[(size_t)gds[r] * 64 + vt * 16 + l15], ex[vt][r] * vv);
            }
    }
}

// ---------------------------------------------------------------------------
// Kernel C: out = (num/(den+1e-16)) @ W_proj + b_proj, persistent.
// ---------------------------------------------------------------------------
__global__ __launch_bounds__(256)
void final_proj_kernel(const float* __restrict__ num, const float* __restrict__ den,
                       const float* __restrict__ Wp, const float* __restrict__ bp,
                       float* __restrict__ out, int N, int ntiles)
{
    __shared__ __align__(16) float sW[64 * 64];
    __shared__ float sb[64];
    __shared__ __align__(16) float at[64][68];

    const int t = threadIdx.x;
    for (int i4 = t; i4 < 1024; i4 += 256)
        ((float4*)sW)[i4] = ((const float4*)Wp)[i4];
    if (t < 64) sb[t] = bp[t];

    const int te = t >> 4, tj = t & 15;
    const int j0 = tj * 4, e0 = te * 4;

    for (int tile = blockIdx.x; tile < ntiles; tile += gridDim.x) {
        const int nbase = tile * 64;
        __syncthreads();
        for (int idx = t; idx < 1024; idx += 256) {
            const int n  = idx >> 4;
            const int c4 = (idx & 15) * 4;
            const int gn = nbase + n;
            float4 g = make_float4(0.f, 0.f, 0.f, 0.f);
            if (gn < N) {
                const float4 nm = *(const float4*)&num[(size_t)gn * 64 + c4];
                const float inv = 1.0f / (den[(size_t)gn * 4 + (c4 >> 4)] + 1e-16f);
                g = make_float4(nm.x * inv, nm.y * inv, nm.z * inv, nm.w * inv);
            }
            *(float4*)&at[n][c4] = g;
        }
        __syncthreads();

        float acc[4][4];
#pragma unroll
        for (int i = 0; i < 4; ++i)
#pragma unroll
            for (int c = 0; c < 4; ++c) acc[i][c] = 0.f;

#pragma unroll 16
        for (int k = 0; k < 64; ++k) {
            const float4 wv = *(const float4*)&sW[k * 64 + j0];
            const float a0 = at[e0 + 0][k], a1 = at[e0 + 1][k];
            const float a2 = at[e0 + 2][k], a3 = at[e0 + 3][k];
            acc[0][0] += a0 * wv.x; acc[0][1] += a0 * wv.y; acc[0][2] += a0 * wv.z; acc[0][3] += a0 * wv.w;
            acc[1][0] += a1 * wv.x; acc[1][1] += a1 * wv.y; acc[1][2] += a1 * wv.z; acc[1][3] += a1 * wv.w;
            acc[2][0] += a2 * wv.x; acc[2][1] += a2 * wv.y; acc[2][2] += a2 * wv.z; acc[2][3] += a2 * wv.w;
            acc[3][0] += a3 * wv.x; acc[3][1] += a3 * wv.y; acc[3][2] += a3 * wv.z; acc[3][3] += a3 * wv.w;
        }

#pragma unroll
        for (int i = 0; i < 4; ++i) {
            const int gn = nbase + e0 + i;
            if (gn >= N) continue;
            float4 o;
            o.x = acc[i][0] + sb[j0 + 0];
            o.y = acc[i][1] + sb[j0 + 1];
            o.z = acc[i][2] + sb[j0 + 2];
            o.w = acc[i][3] + sb[j0 + 3];
            *(float4*)&out[(size_t)gn * 64 + j0] = o;
        }
    }
}

// ---------------------------------------------------------------------------
extern "C" void kernel_launch(void* const* d_in, const int* in_sizes, int n_in,
                              void* d_out, int out_size, void* d_ws, size_t ws_size,
                              hipStream_t stream)
{
    const float* node_input = (const float*)d_in[0];
    const int*   edge_src   = (const int*)  d_in[2];
    const int*   edge_dst   = (const int*)  d_in[3];
    const float* edge_attr  = (const float*)d_in[4];
    const float* edge_scal  = (const float*)d_in[5];
    const float* Wq    = (const float*)d_in[7];
    const float* bq    = (const float*)d_in[8];
    const float* W_src = (const float*)d_in[9];
    const float* b_src = (const float*)d_in[10];
    const float* W_dst = (const float*)d_in[11];
    const float* W_fc1 = (const float*)d_in[12];
    const float* b_fc1 = (const float*)d_in[13];
    const float* W_fc2 = (const float*)d_in[14];
    const float* b_fc2 = (const float*)d_in[15];
    const float* W_fc3 = (const float*)d_in[16];
    const float* b_fc3 = (const float*)d_in[17];
    const float* W_kv  = (const float*)d_in[18];
    const float* b_kv  = (const float*)d_in[19];
    const float* W_proj = (const float*)d_in[20];
    const float* b_proj = (const float*)d_in[21];

    const int N = in_sizes[0] / 64;    // 50000
    const int E = in_sizes[2];         // 800000

    float* ws    = (float*)d_ws;
    float* q_buf = ws;                        // N*64
    float* msrc  = ws + (size_t)N * 64;       // N*64
    float* mdst  = ws + (size_t)N * 128;      // N*64
    float* num   = ws + (size_t)N * 192;      // N*64
    float* den   = ws + (size_t)N * 256;      // N*4
    unsigned short* wbf = (unsigned short*)(ws + (size_t)N * 260);  // 20480 ushort

    hipMemsetAsync(num, 0, (size_t)N * 68 * sizeof(float), stream);

    // one-time bf16 pre-swizzled weight images
    prep_weights<<<80, 256, 0, stream>>>(W_fc1, W_fc2, W_fc3, W_kv, wbf);

    {
        const int ntiles = (N + 31) / 32;     // 1563
        node_linear_kernel<<<512, 384, 0, stream>>>(node_input, Wq, bq, W_src, b_src, W_dst,
                                                    q_buf, msrc, mdst, N, ntiles);
    }
    {
        const int ntiles = E / 128;           // 6250
        edge_fused_mfma<<<512, 512, 0, stream>>>(edge_src, edge_dst, edge_attr, edge_scal,
                                                 wbf, b_fc1, b_fc2, b_fc3, b_kv,
                                                 q_buf, msrc, mdst, num, den, ntiles);
    }
    {
        const int ntiles = (N + 63) / 64;     // 782
        final_proj_kernel<<<512, 256, 0, stream>>>(num, den, W_proj, b_proj,
                                                   (float*)d_out, N, ntiles);
    }
}

// Round 8
// 671.999 us; speedup vs baseline: 1.8059x; 1.0003x over previous
//
#include <hip/hip_runtime.h>
#include <hip/hip_bf16.h>

// N_NODES=50000, N_EDGES=800000, C_IN=64, N_HEADS=4, HEAD_DIM=16, FC=64
// Edge tile: 128 edges, 512 threads (8 waves), bf16 MFMA chain.
// R8: BARRIER-FREE edge kernel — all per-tile state is wave-private
// (rows [16w,16w+16) of sA0/sA1); only one __syncthreads after the one-time
// weight stage. Cross-lane LDS write->read within a wave is ordered by the
// in-order per-wave LDS pipe; asm memory fences stop compiler reordering.

typedef __attribute__((ext_vector_type(8))) short    bf16x8;
typedef __attribute__((ext_vector_type(4))) float    f32x4;
typedef __attribute__((ext_vector_type(4))) unsigned short ushort4v;

__device__ __forceinline__ unsigned short f2bf(float x) {
    union { float f; unsigned u; } v; v.f = x;
    unsigned r = v.u + 0x7fffu + ((v.u >> 16) & 1u);   // round-to-nearest-even
    return (unsigned short)(r >> 16);
}

// swizzled ushort index for a [*][64]-bf16 LDS tile (T2 XOR swizzle)
__device__ __forceinline__ int swz(int row, int k) {
    return row * 64 + (k ^ ((row & 7) << 3));
}

// MFMA fragment load: 8 contiguous bf16 at (row|n, k = kk*32 + lhi*8)
__device__ __forceinline__ bf16x8 ldfrag(const unsigned short* buf, int rn, int kk, int lhi) {
    return *(const bf16x8*)(buf + swz(rn, kk * 32 + lhi * 8));
}

#define PHASE_FENCE() asm volatile("" ::: "memory")

// ---------------------------------------------------------------------------
// Kernel P: one-time weight conversion to bf16, PRE-SWIZZLED, into d_ws.
// ---------------------------------------------------------------------------
__global__ __launch_bounds__(256)
void prep_weights(const float* __restrict__ W1, const float* __restrict__ W2,
                  const float* __restrict__ W3, const float* __restrict__ Wkv,
                  unsigned short* __restrict__ wbf)
{
    const int d = blockIdx.x * 256 + threadIdx.x;      // 0..20479
    if (d < 12288) {
        const int w  = d >> 12;
        const int r  = d & 4095;
        const int n  = r >> 6, kx = r & 63;
        const int k  = kx ^ ((n & 7) << 3);
        const float* W = (w == 0) ? W1 : (w == 1) ? W2 : W3;
        wbf[d] = f2bf(W[k * 64 + n]);
    } else if (d < 20480) {
        const int r  = d - 12288;
        const int n  = r >> 6, kx = r & 63;             // n: 0..127
        const int k  = kx ^ ((n & 7) << 3);
        wbf[d] = f2bf(Wkv[k * 128 + n]);
    }
}

// ---------------------------------------------------------------------------
// Kernel A: node-side linears, persistent (unchanged from R7).
// ---------------------------------------------------------------------------
__global__ __launch_bounds__(384)
void node_linear_kernel(const float* __restrict__ x,
                        const float* __restrict__ Wq,   const float* __restrict__ bq,
                        const float* __restrict__ Wsrc, const float* __restrict__ bsrc,
                        const float* __restrict__ Wdst,
                        float* __restrict__ qout, float* __restrict__ msout,
                        float* __restrict__ mdout, int N, int ntiles)
{
    __shared__ __align__(16) float sW[64 * 192];
    __shared__ float sb[192];
    __shared__ __align__(16) float xs[32][68];

    const int t = threadIdx.x;
    for (int idx4 = t; idx4 < 3072; idx4 += 384) {
        const int k  = idx4 / 48;
        const int j4 = idx4 % 48;
        const float4* src = (j4 < 16) ? (const float4*)&Wq  [k * 64 + j4 * 4]
                         : (j4 < 32) ? (const float4*)&Wsrc[k * 64 + (j4 - 16) * 4]
                                     : (const float4*)&Wdst[k * 64 + (j4 - 32) * 4];
        ((float4*)sW)[idx4] = *src;
    }
    if (t < 192) sb[t] = (t < 64) ? bq[t] : (t < 128) ? bsrc[t - 64] : 0.0f;

    const int te = t / 48, tj = t % 48;
    const int j0 = tj * 4, e0 = te * 4;

    for (int tile = blockIdx.x; tile < ntiles; tile += gridDim.x) {
        const int nbase = tile * 32;
        __syncthreads();                       // weights ready / prev xs consumed
        for (int idx = t; idx < 512; idx += 384) {
            const int n  = idx >> 4;
            const int c4 = (idx & 15) * 4;
            const int gn = nbase + n;
            float4 g = make_float4(0.f, 0.f, 0.f, 0.f);
            if (gn < N) g = *(const float4*)&x[(size_t)gn * 64 + c4];
            *(float4*)&xs[n][c4] = g;
        }
        __syncthreads();

        float acc[4][4];
#pragma unroll
        for (int i = 0; i < 4; ++i)
#pragma unroll
            for (int c = 0; c < 4; ++c) acc[i][c] = 0.f;

#pragma unroll 16
        for (int k = 0; k < 64; ++k) {
            const float4 wv = *(const float4*)&sW[k * 192 + j0];
            const float a0 = xs[e0 + 0][k], a1 = xs[e0 + 1][k];
            const float a2 = xs[e0 + 2][k], a3 = xs[e0 + 3][k];
            acc[0][0] += a0 * wv.x; acc[0][1] += a0 * wv.y; acc[0][2] += a0 * wv.z; acc[0][3] += a0 * wv.w;
            acc[1][0] += a1 * wv.x; acc[1][1] += a1 * wv.y; acc[1][2] += a1 * wv.z; acc[1][3] += a1 * wv.w;
            acc[2][0] += a2 * wv.x; acc[2][1] += a2 * wv.y; acc[2][2] += a2 * wv.z; acc[2][3] += a2 * wv.w;
            acc[3][0] += a3 * wv.x; acc[3][1] += a3 * wv.y; acc[3][2] += a3 * wv.z; acc[3][3] += a3 * wv.w;
        }

#pragma unroll
        for (int i = 0; i < 4; ++i) {
            const int gn = nbase + e0 + i;
            if (gn >= N) continue;
            float4 o;
            o.x = acc[i][0] + sb[j0 + 0];
            o.y = acc[i][1] + sb[j0 + 1];
            o.z = acc[i][2] + sb[j0 + 2];
            o.w = acc[i][3] + sb[j0 + 3];
            if (j0 < 64) {
                o.x *= 0.25f; o.y *= 0.25f; o.z *= 0.25f; o.w *= 0.25f;
                *(float4*)&qout[(size_t)gn * 64 + j0] = o;
            } else if (j0 < 128) {
                *(float4*)&msout[(size_t)gn * 64 + (j0 - 64)] = o;
            } else {
                *(float4*)&mdout[(size_t)gn * 64 + (j0 - 128)] = o;
            }
        }
    }
}

// ---------------------------------------------------------------------------
// Kernel B (MFMA): fused per-edge chain, persistent, BARRIER-FREE main loop.
// ---------------------------------------------------------------------------
__global__ __launch_bounds__(512, 4)
void edge_fused_mfma(const int* __restrict__ esrc, const int* __restrict__ edst,
                     const float* __restrict__ eattr, const float* __restrict__ escal,
                     const unsigned short* __restrict__ wbf,
                     const float* __restrict__ b1, const float* __restrict__ b2,
                     const float* __restrict__ b3, const float* __restrict__ bkv,
                     const float* __restrict__ qbuf, const float* __restrict__ msrc,
                     const float* __restrict__ mdst,
                     float* __restrict__ num, float* __restrict__ den, int ntiles)
{
    __shared__ __align__(16) unsigned short sh[36864];  // 73728 B
    unsigned short* sW1t  = sh;           // [64][64] bf16, transposed+swz
    unsigned short* sW2t  = sh + 4096;
    unsigned short* sW3t  = sh + 8192;
    unsigned short* sWkvt = sh + 12288;   // [128][64]
    unsigned short* sA0   = sh + 20480;   // [128 edges][64] act ping (wave-private rows)
    unsigned short* sA1   = sh + 28672;   // act pong
    __shared__ float sB1[64], sB2[64], sB3[64], sBkv[128];

    const int t    = threadIdx.x;
    const int lane = t & 63;
    const int wave = t >> 6;
    const int l15  = lane & 15;
    const int lhi  = lane >> 4;          // 0..3
    const int rowBase = wave * 16;
    const int r4   = lhi * 4;            // first D-row (within wave) this lane owns

    // ---- one-time stage: all weights (pre-swizzled bf16) + biases ----
    for (int i4 = t; i4 < 2560; i4 += 512)
        ((float4*)sh)[i4] = ((const float4*)wbf)[i4];
    if (t < 64)              { sB1[t] = b1[t]; sB2[t] = b2[t]; sB3[t] = b3[t]; }
    if (t >= 64 && t < 192)  sBkv[t - 64] = bkv[t - 64];
    __syncthreads();                     // the ONLY block-wide barrier

    // stage-load mapping: per p, lanes cover 4 rows x 64 floats contiguously
    const int srow = lane >> 4;          // 0..3 (row-within-quad)
    const int scol = (lane & 15) << 2;   // 0..60 (float col)

    for (int tile = blockIdx.x; tile < ntiles; tile += gridDim.x) {
        const int base  = tile * 128;
        const int ebase = base + rowBase;

        // ---- per-wave stage: 16 rows of escal -> sA0 (bf16, swz) ----
#pragma unroll
        for (int p = 0; p < 4; ++p) {
            const int row = p * 4 + srow;   // 0..15 within wave
            const float4 g = *(const float4*)&escal[(size_t)(ebase + row) * 64 + scol];
            ushort4v pk = { f2bf(g.x), f2bf(g.y), f2bf(g.z), f2bf(g.w) };
            *(ushort4v*)&sA0[swz(rowBase + row, scol)] = pk;
        }

        // ---- per-lane metadata for this lane's 4 D-rows ----
        int   gsrc[4], gdst[4];
        float gea[4];
#pragma unroll
        for (int r = 0; r < 4; ++r) {
            const int e = ebase + r4 + r;
            gsrc[r] = esrc[e];
            gdst[r] = edst[e];
            gea[r]  = eattr[e];
        }
        // hoisted q gather: only depends on gdst; latency hides under the MLP
        float qreg[4][4];
#pragma unroll
        for (int h = 0; h < 4; ++h)
#pragma unroll
            for (int r = 0; r < 4; ++r)
                qreg[h][r] = qbuf[(size_t)gdst[r] * 64 + h * 16 + l15];

        PHASE_FENCE();   // stage stores precede L1 frag reads

        // ================= Layer 1: silu(es@W1+b1) : sA0 -> sA1 =============
        {
            f32x4 acc[4] = {{0,0,0,0},{0,0,0,0},{0,0,0,0},{0,0,0,0}};
#pragma unroll
            for (int kk = 0; kk < 2; ++kk) {
                const bf16x8 a = ldfrag(sA0, rowBase + l15, kk, lhi);
#pragma unroll
                for (int c = 0; c < 4; ++c) {
                    const bf16x8 b = ldfrag(sW1t, c * 16 + l15, kk, lhi);
                    acc[c] = __builtin_amdgcn_mfma_f32_16x16x32_bf16(a, b, acc[c], 0, 0, 0);
                }
            }
#pragma unroll
            for (int c = 0; c < 4; ++c)
#pragma unroll
                for (int r = 0; r < 4; ++r) {
                    const int row = rowBase + r4 + r;
                    const int col = c * 16 + l15;
                    const float v = acc[c][r] + sB1[col];
                    sA1[swz(row, col)] = f2bf(v / (1.f + __expf(-v)));
                }
        }
        PHASE_FENCE();

        // ================= Layer 2: silu(h1@W2+b2) : sA1 -> sA0 =============
        {
            f32x4 acc[4] = {{0,0,0,0},{0,0,0,0},{0,0,0,0},{0,0,0,0}};
#pragma unroll
            for (int kk = 0; kk < 2; ++kk) {
                const bf16x8 a = ldfrag(sA1, rowBase + l15, kk, lhi);
#pragma unroll
                for (int c = 0; c < 4; ++c) {
                    const bf16x8 b = ldfrag(sW2t, c * 16 + l15, kk, lhi);
                    acc[c] = __builtin_amdgcn_mfma_f32_16x16x32_bf16(a, b, acc[c], 0, 0, 0);
                }
            }
#pragma unroll
            for (int c = 0; c < 4; ++c)
#pragma unroll
                for (int r = 0; r < 4; ++r) {
                    const int row = rowBase + r4 + r;
                    const int col = c * 16 + l15;
                    const float v = acc[c][r] + sB2[col];
                    sA0[swz(row, col)] = f2bf(v / (1.f + __expf(-v)));
                }
        }
        PHASE_FENCE();

        // ===== Layer 3 + tp: w = h2@W3+b3; tp=(msrc[s]+mdst[d])*ea*w ========
        {
            f32x4 acc[4] = {{0,0,0,0},{0,0,0,0},{0,0,0,0},{0,0,0,0}};
#pragma unroll
            for (int kk = 0; kk < 2; ++kk) {
                const bf16x8 a = ldfrag(sA0, rowBase + l15, kk, lhi);
#pragma unroll
                for (int c = 0; c < 4; ++c) {
                    const bf16x8 b = ldfrag(sW3t, c * 16 + l15, kk, lhi);
                    acc[c] = __builtin_amdgcn_mfma_f32_16x16x32_bf16(a, b, acc[c], 0, 0, 0);
                }
            }
            float ms[4][4], md[4][4];
#pragma unroll
            for (int c = 0; c < 4; ++c)
#pragma unroll
                for (int r = 0; r < 4; ++r) {
                    const int col = c * 16 + l15;
                    ms[c][r] = msrc[(size_t)gsrc[r] * 64 + col];
                    md[c][r] = mdst[(size_t)gdst[r] * 64 + col];
                }
#pragma unroll
            for (int c = 0; c < 4; ++c)
#pragma unroll
                for (int r = 0; r < 4; ++r) {
                    const int row = rowBase + r4 + r;
                    const int col = c * 16 + l15;
                    const float w  = acc[c][r] + sB3[col];
                    const float tp = (ms[c][r] + md[c][r]) * gea[r] * w;
                    sA1[swz(row, col)] = f2bf(tp);
                }
        }
        PHASE_FENCE();

        // ============ kv2 = tp@Wkv (+bkv): k cols 0..63, v cols 64..127 =====
        f32x4 acc2[8] = {{0,0,0,0},{0,0,0,0},{0,0,0,0},{0,0,0,0},
                         {0,0,0,0},{0,0,0,0},{0,0,0,0},{0,0,0,0}};
#pragma unroll
        for (int kk = 0; kk < 2; ++kk) {
            const bf16x8 a = ldfrag(sA1, rowBase + l15, kk, lhi);
#pragma unroll
            for (int c = 0; c < 8; ++c) {
                const bf16x8 b = ldfrag(sWkvt, c * 16 + l15, kk, lhi);
                acc2[c] = __builtin_amdgcn_mfma_f32_16x16x32_bf16(a, b, acc2[c], 0, 0, 0);
            }
        }

        // ================= alpha, exp, atomics ==============================
        float ex[4][4];
#pragma unroll
        for (int h = 0; h < 4; ++h)
#pragma unroll
            for (int r = 0; r < 4; ++r) {
                float s = (acc2[h][r] + sBkv[h * 16 + l15]) * qreg[h][r];
                s += __shfl_xor(s, 1);
                s += __shfl_xor(s, 2);
                s += __shfl_xor(s, 4);
                s += __shfl_xor(s, 8);
                const float e = __expf(s);
                ex[h][r] = e;
                if (l15 == h * 4 + r) atomicAdd(&den[(size_t)gdst[r] * 4 + h], e);
            }

#pragma unroll
        for (int vt = 0; vt < 4; ++vt)
#pragma unroll
            for (int r = 0; r < 4; ++r) {
                const float vv = acc2[4 + vt][r] + sBkv[64 + vt * 16 + l15];
                atomicAdd(&num[(size_t)gdst[r] * 64 + vt * 16 + l15], ex[vt][r] * vv);
            }

        PHASE_FENCE();   // this tile's sA0/sA1 reads precede next tile's stage
    }
}

// ---------------------------------------------------------------------------
// Kernel C: out = (num/(den+1e-16)) @ W_proj + b_proj, persistent (unchanged).
// ---------------------------------------------------------------------------
__global__ __launch_bounds__(256)
void final_proj_kernel(const float* __restrict__ num, const float* __restrict__ den,
                       const float* __restrict__ Wp, const float* __restrict__ bp,
                       float* __restrict__ out, int N, int ntiles)
{
    __shared__ __align__(16) float sW[64 * 64];
    __shared__ float sb[64];
    __shared__ __align__(16) float at[64][68];

    const int t = threadIdx.x;
    for (int i4 = t; i4 < 1024; i4 += 256)
        ((float4*)sW)[i4] = ((const float4*)Wp)[i4];
    if (t < 64) sb[t] = bp[t];

    const int te = t >> 4, tj = t & 15;
    const int j0 = tj * 4, e0 = te * 4;

    for (int tile = blockIdx.x; tile < ntiles; tile += gridDim.x) {
        const int nbase = tile * 64;
        __syncthreads();
        for (int idx = t; idx < 1024; idx += 256) {
            const int n  = idx >> 4;
            const int c4 = (idx & 15) * 4;
            const int gn = nbase + n;
            float4 g = make_float4(0.f, 0.f, 0.f, 0.f);
            if (gn < N) {
                const float4 nm = *(const float4*)&num[(size_t)gn * 64 + c4];
                const float inv = 1.0f / (den[(size_t)gn * 4 + (c4 >> 4)] + 1e-16f);
                g = make_float4(nm.x * inv, nm.y * inv, nm.z * inv, nm.w * inv);
            }
            *(float4*)&at[n][c4] = g;
        }
        __syncthreads();

        float acc[4][4];
#pragma unroll
        for (int i = 0; i < 4; ++i)
#pragma unroll
            for (int c = 0; c < 4; ++c) acc[i][c] = 0.f;

#pragma unroll 16
        for (int k = 0; k < 64; ++k) {
            const float4 wv = *(const float4*)&sW[k * 64 + j0];
            const float a0 = at[e0 + 0][k], a1 = at[e0 + 1][k];
            const float a2 = at[e0 + 2][k], a3 = at[e0 + 3][k];
            acc[0][0] += a0 * wv.x; acc[0][1] += a0 * wv.y; acc[0][2] += a0 * wv.z; acc[0][3] += a0 * wv.w;
            acc[1][0] += a1 * wv.x; acc[1][1] += a1 * wv.y; acc[1][2] += a1 * wv.z; acc[1][3] += a1 * wv.w;
            acc[2][0] += a2 * wv.x; acc[2][1] += a2 * wv.y; acc[2][2] += a2 * wv.z; acc[2][3] += a2 * wv.w;
            acc[3][0] += a3 * wv.x; acc[3][1] += a3 * wv.y; acc[3][2] += a3 * wv.z; acc[3][3] += a3 * wv.w;
        }

#pragma unroll
        for (int i = 0; i < 4; ++i) {
            const int gn = nbase + e0 + i;
            if (gn >= N) continue;
            float4 o;
            o.x = acc[i][0] + sb[j0 + 0];
            o.y = acc[i][1] + sb[j0 + 1];
            o.z = acc[i][2] + sb[j0 + 2];
            o.w = acc[i][3] + sb[j0 + 3];
            *(float4*)&out[(size_t)gn * 64 + j0] = o;
        }
    }
}

// ---------------------------------------------------------------------------
extern "C" void kernel_launch(void* const* d_in, const int* in_sizes, int n_in,
                              void* d_out, int out_size, void* d_ws, size_t ws_size,
                              hipStream_t stream)
{
    const float* node_input = (const float*)d_in[0];
    const int*   edge_src   = (const int*)  d_in[2];
    const int*   edge_dst   = (const int*)  d_in[3];
    const float* edge_attr  = (const float*)d_in[4];
    const float* edge_scal  = (const float*)d_in[5];
    const float* Wq    = (const float*)d_in[7];
    const float* bq    = (const float*)d_in[8];
    const float* W_src = (const float*)d_in[9];
    const float* b_src = (const float*)d_in[10];
    const float* W_dst = (const float*)d_in[11];
    const float* W_fc1 = (const float*)d_in[12];
    const float* b_fc1 = (const float*)d_in[13];
    const float* W_fc2 = (const float*)d_in[14];
    const float* b_fc2 = (const float*)d_in[15];
    const float* W_fc3 = (const float*)d_in[16];
    const float* b_fc3 = (const float*)d_in[17];
    const float* W_kv  = (const float*)d_in[18];
    const float* b_kv  = (const float*)d_in[19];
    const float* W_proj = (const float*)d_in[20];
    const float* b_proj = (const float*)d_in[21];

    const int N = in_sizes[0] / 64;    // 50000
    const int E = in_sizes[2];         // 800000

    float* ws    = (float*)d_ws;
    float* q_buf = ws;                        // N*64
    float* msrc  = ws + (size_t)N * 64;       // N*64
    float* mdst  = ws + (size_t)N * 128;      // N*64
    float* num   = ws + (size_t)N * 192;      // N*64
    float* den   = ws + (size_t)N * 256;      // N*4
    unsigned short* wbf = (unsigned short*)(ws + (size_t)N * 260);  // 20480 ushort

    hipMemsetAsync(num, 0, (size_t)N * 68 * sizeof(float), stream);

    // one-time bf16 pre-swizzled weight images
    prep_weights<<<80, 256, 0, stream>>>(W_fc1, W_fc2, W_fc3, W_kv, wbf);

    {
        const int ntiles = (N + 31) / 32;     // 1563
        node_linear_kernel<<<512, 384, 0, stream>>>(node_input, Wq, bq, W_src, b_src, W_dst,
                                                    q_buf, msrc, mdst, N, ntiles);
    }
    {
        const int ntiles = E / 128;           // 6250
        edge_fused_mfma<<<512, 512, 0, stream>>>(edge_src, edge_dst, edge_attr, edge_scal,
                                                 wbf, b_fc1, b_fc2, b_fc3, b_kv,
                                                 q_buf, msrc, mdst, num, den, ntiles);
    }
    {
        const int ntiles = (N + 63) / 64;     // 782
        final_proj_kernel<<<512, 256, 0, stream>>>(num, den, W_proj, b_proj,
                                                   (float*)d_out, N, ntiles);
    }
}